// Round 4
// baseline (467.089 us; speedup 1.0000x reference)
//
#include <hip/hip_runtime.h>
#include <hip/hip_bf16.h>
#include <cstdint>

// Problem constants: T=512 timesteps/slots, B=64 batch, E=512 embed.
#define TT 512
#define BB 64
#define EE 512

#define CH_STR 36            // shorts per e-row of a chunk (72B: bank-floor, 8B-aligned)
#define CH_SZ  (64 * CH_STR) // shorts per chunk [64e][32k + pad]

typedef short bf16x8 __attribute__((ext_vector_type(8)));   // MFMA A/B frag
typedef float f32x4  __attribute__((ext_vector_type(4)));   // MFMA C/D frag

// RNE pack of (a -> low16, b -> high16); compiler emits v_cvt_pk_bf16_f32.
static __device__ __forceinline__ unsigned bpack(float a, float b) {
    union { __hip_bfloat162 h; unsigned u; } cv;
    cv.h = __float22bfloat162_rn(make_float2(a, b));
    return cv.u;
}

// Barrier that does NOT drain vmcnt: LDS traffic made visible (lgkmcnt(0)),
// in-flight global register prefetches stay outstanding.
static __device__ __forceinline__ void barrier_lds_only() {
    asm volatile("s_waitcnt lgkmcnt(0)" ::: "memory");
    __builtin_amdgcn_s_barrier();
}

// ---------------------------------------------------------------------------
// Chunk-major, accumulator-resident V-resident design.
//   Block owns ONE (batch b, 64-col e-slice), ALL 512 m-rows. Full V slice in
//   LDS as bf16 (16 chunks x [64e][32k], stride-36 rows = 72 KB; +Rs/CUs 4KB
//   = 77.8 KB -> 2 blocks/CU). V fetched from HBM exactly once.
//
//   wave-0 prologue: queue scan (closed form, max-plus wave scan) -> Rs/CUs.
//     C[t,i] = clamp(R_i - cu_t,0,1) - clamp(R_{i-1} - cu_t,0,1)  (0 for i>t)
//
//   Main loop over 8 chunk-PAIRS (one barrier each): issue pair pp+2 loads,
//   pack pair pp+1 (write-once slots), consume chunks 2pp, 2pp+1, barrier.
//
//   Consumption is chunk-major: wave w owns eight 16-row groups g = w + 4*gi
//   (interleaved -> per-chunk demand balanced across waves). Per (chunk,
//   active group): ONE in-register af-compute feeds FOUR MFMAs (vs 2 in r3,
//   and no cross-wave duplication) -- A-VALU per MFMA halved. B-frags and
//   rv are loaded once per chunk and reused across groups. acc[8][4] stays
//   resident (128 VGPR); each group flushes right after its diagonal chunk,
//   spreading stores across the kernel.
//
//   LDS bank floor: rows at 72B; all chunk accesses 8B (b64). Write starts
//   4(m+w) mod 32 (8 groups, was 1 in r3 -> 3.0M conflict cycles); read
//   starts 18f+4q mod 32 -> all 32 banks, 4 deep (exact floor).
// Grid: 512 blocks x 256 threads (64 b x 8 slices), 2 blocks/CU.
// ---------------------------------------------------------------------------
__global__ __launch_bounds__(256, 2) void queue_fused_kernel(
        const float* __restrict__ V,    // [T(i)][B][E]
        const float* __restrict__ U,    // [T][B]
        const float* __restrict__ D,    // [T][B]
        float* __restrict__ out) {      // [T(t)][B][E]
    const int id    = blockIdx.x;
    const int slice = id & 7;
    const int b     = id >> 3;
    const int n0    = slice * 64;

    __shared__ __align__(16) unsigned short Vs[16 * CH_SZ];
    __shared__ __align__(16) float Rs[TT];
    __shared__ __align__(16) float CUs[TT];

    const int tid  = threadIdx.x;
    const int wave = tid >> 6;
    const int lane = tid & 63;

    // Stage mapping: lanes 0-31 pack chunk 2pp, lanes 32-63 chunk 2pp+1.
    const int c_sel = lane >> 5;
    const int m5    = lane & 31;
    const int e2    = m5 * 2;
    const int k8    = wave * 8;
    // Fragment mapping.
    const int frow = lane & 15;
    const int quad = lane >> 4;

    const float* Vbase = V + (size_t)b * EE + n0 + e2;

    float2 vA[8], vB[8];                  // 2-deep (pair-granular) prefetch

    auto issueL = [&](float2 (&v)[8], int pair) {
        const float* p = Vbase + (size_t)((pair * 2 + c_sel) * 32 + k8) * (BB * EE);
        #pragma unroll
        for (int r = 0; r < 8; ++r)
            v[r] = *(const float2*)(p + (size_t)r * (BB * EE));
    };
    auto packW = [&](float2 (&v)[8], int pair) {
        uint2 q0, q1, q2, q3;
        q0.x = bpack(v[0].x, v[1].x); q0.y = bpack(v[2].x, v[3].x);
        q1.x = bpack(v[4].x, v[5].x); q1.y = bpack(v[6].x, v[7].x);
        q2.x = bpack(v[0].y, v[1].y); q2.y = bpack(v[2].y, v[3].y);
        q3.x = bpack(v[4].y, v[5].y); q3.y = bpack(v[6].y, v[7].y);
        unsigned short* dst = Vs + (pair * 2 + c_sel) * CH_SZ + e2 * CH_STR + k8;
        *(uint2*)(dst)              = q0;   // row e2,   k8..k8+3
        *(uint2*)(dst + 4)          = q1;   // row e2,   k8+4..k8+7
        *(uint2*)(dst + CH_STR)     = q2;   // row e2+1, k8..k8+3
        *(uint2*)(dst + CH_STR + 4) = q3;   // row e2+1, k8+4..k8+7
    };

    // ---- Prologue ----
    float su[8], sd[8];
    if (wave == 0) {                      // U/D first: V-waits imply they're done
        #pragma unroll
        for (int j = 0; j < 8; ++j) {
            su[j] = U[(lane * 8 + j) * BB + b];
            sd[j] = D[(lane * 8 + j) * BB + b];
        }
    }
    issueL(vA, 0);
    issueL(vB, 1);                        // stays in flight
    packW(vA, 0);                         // waits vA only

    if (wave == 0) {                      // queue scan -> Rs/CUs
        float A = 0.f, Bv = -1e30f, S = 0.f;
        #pragma unroll
        for (int j = 0; j < 8; ++j) {
            const float a = sd[j] - su[j];
            Bv = fmaxf(Bv + a, sd[j]);
            A += a;
            S += su[j];
        }
        #pragma unroll
        for (int off = 1; off < 64; off <<= 1) {
            const float Ap = __shfl_up(A, off);
            const float Bp = __shfl_up(Bv, off);
            const float Sp = __shfl_up(S, off);
            if (lane >= off) {
                Bv = fmaxf(Bp + A, Bv);
                A  = A + Ap;
                S  = S + Sp;
            }
        }
        float Aex = __shfl_up(A, 1), Bex = __shfl_up(Bv, 1), Sex = __shfl_up(S, 1);
        if (lane == 0) { Aex = 0.f; Bex = -1e30f; Sex = 0.f; }
        float Q  = fmaxf(Aex, Bex);
        float cu = Sex;
        float rw[8], cw[8];
        #pragma unroll
        for (int j = 0; j < 8; ++j) {
            cu += su[j];
            Q = fmaxf(Q - su[j], 0.f) + sd[j];
            rw[j] = Q + cu;
            cw[j] = cu;
        }
        *(float4*)(Rs  + lane * 8)     = make_float4(rw[0], rw[1], rw[2], rw[3]);
        *(float4*)(Rs  + lane * 8 + 4) = make_float4(rw[4], rw[5], rw[6], rw[7]);
        *(float4*)(CUs + lane * 8)     = make_float4(cw[0], cw[1], cw[2], cw[3]);
        *(float4*)(CUs + lane * 8 + 4) = make_float4(cw[4], cw[5], cw[6], cw[7]);
    }
    barrier_lds_only();                   // publishes pair 0 + Rs/CUs

    // Per-group cu_t, resident for the whole kernel (broadcast-friendly reads).
    float cuR[8];
    #pragma unroll
    for (int gi = 0; gi < 8; ++gi)
        cuR[gi] = CUs[16 * (wave + 4 * gi) + frow];

    f32x4 acc[8][4];
    #pragma unroll
    for (int gi = 0; gi < 8; ++gi)
        #pragma unroll
        for (int ni = 0; ni < 4; ++ni)
            acc[gi][ni] = f32x4{0.f, 0.f, 0.f, 0.f};

    // Consume one 32-k chunk: B-frags + rv once, then all active groups.
    auto consume = [&](int kk) {
        const int i0 = kk * 32 + quad * 8;
        uint2 bfl[4], bfh[4];
        #pragma unroll
        for (int ni = 0; ni < 4; ++ni) {
            const unsigned short* sp =
                Vs + kk * CH_SZ + (ni * 16 + frow) * CH_STR + quad * 8;
            bfl[ni] = *(const uint2*)(sp);
            bfh[ni] = *(const uint2*)(sp + 4);
        }
        const float4 r0 = *(const float4*)(Rs + i0);
        const float4 r1 = *(const float4*)(Rs + i0 + 4);
        const float rv[8] = {r0.x, r0.y, r0.z, r0.w, r1.x, r1.y, r1.z, r1.w};
        const float prevR = (i0 == 0) ? 0.f : Rs[i0 - 1];

        #pragma unroll
        for (int gi = 0; gi < 8; ++gi) {
            const int g = wave + 4 * gi;           // 16-row group index
            if (g < 2 * kk) continue;              // uniform: group done
            const float cu = cuR[gi];
            float pvp = fminf(fmaxf(prevR - cu, 0.f), 1.f);
            float c[8];
            #pragma unroll
            for (int j = 0; j < 8; ++j) {
                const float pv = fminf(fmaxf(rv[j] - cu, 0.f), 1.f);
                c[j] = pv - pvp;
                pvp = pv;
            }
            const bool last = ((g >> 1) == kk);    // diagonal chunk
            if (last) {
                const int rel = 16 * g + frow - i0;
                #pragma unroll
                for (int j = 0; j < 8; ++j)
                    c[j] = (j <= rel) ? c[j] : 0.f;
            }
            union { unsigned u[4]; bf16x8 v; } af;
            af.u[0] = bpack(c[0], c[1]); af.u[1] = bpack(c[2], c[3]);
            af.u[2] = bpack(c[4], c[5]); af.u[3] = bpack(c[6], c[7]);
            #pragma unroll
            for (int ni = 0; ni < 4; ++ni) {
                union { struct { uint2 l, h; } p; bf16x8 v; } bfu;
                bfu.p.l = bfl[ni]; bfu.p.h = bfh[ni];
                acc[gi][ni] = __builtin_amdgcn_mfma_f32_16x16x32_bf16(
                    af.v, bfu.v, acc[gi][ni], 0, 0, 0);
            }
            if (last) {                            // flush completed group
                // C/D layout col=lane&15, row=quad*4+r (m89/m91 verified).
                #pragma unroll
                for (int r = 0; r < 4; ++r) {
                    const int t = 16 * g + quad * 4 + r;
                    float* orow = out + ((size_t)t * BB + b) * EE + n0;
                    #pragma unroll
                    for (int ni = 0; ni < 4; ++ni)
                        orow[ni * 16 + frow] = acc[gi][ni][r];
                }
            }
        }
    };

    auto interval = [&](int pp, float2 (&vcur)[8], float2 (&vnxt)[8]) {
        if (pp < 6) issueL(vnxt, pp + 2);   // issue-early, lands next interval
        if (pp < 7) packW(vcur, pp + 1);    // write-once into fresh slots
        consume(2 * pp);
        consume(2 * pp + 1);
        if (pp < 7) barrier_lds_only();     // publish pair pp+1
    };

    for (int pp = 0; pp < 8; pp += 2) {
        interval(pp,     vB, vA);           // pair pp+1 lives in vB
        interval(pp + 1, vA, vB);
    }
}

extern "C" void kernel_launch(void* const* d_in, const int* in_sizes, int n_in,
                              void* d_out, int out_size, void* d_ws, size_t ws_size,
                              hipStream_t stream) {
    const float* V = (const float*)d_in[0];   // [T,B,E]
    const float* U = (const float*)d_in[1];   // [T,B]
    const float* D = (const float*)d_in[2];   // [T,B]
    float* out = (float*)d_out;               // [T,B,E]

    queue_fused_kernel<<<dim3(512), dim3(256), 0, stream>>>(V, U, D, out);
}

// Round 5
// 131.565 us; speedup vs baseline: 3.5502x; 3.5502x over previous
//
#include <hip/hip_runtime.h>
#include <hip/hip_bf16.h>
#include <cstdint>

// Problem constants: T=512 timesteps/slots, B=64 batch, E=512 embed.
#define TT 512
#define BB 64
#define EE 512

typedef short bf16x8 __attribute__((ext_vector_type(8)));   // 8 bf16 = 4 VGPRs
typedef float f32x4  __attribute__((ext_vector_type(4)));   // MFMA C/D frag

// RNE pack of (a -> low16, b -> high16); compiler emits v_cvt_pk_bf16_f32.
static __device__ __forceinline__ unsigned bpack(float a, float b) {
    union { __hip_bfloat162 h; unsigned u; } cv;
    cv.h = __float22bfloat162_rn(make_float2(a, b));
    return cv.u;
}

// Barrier that does NOT drain vmcnt: LDS traffic is made visible
// (lgkmcnt(0)), in-flight global register prefetches stay outstanding.
static __device__ __forceinline__ void barrier_lds_only() {
    asm volatile("s_waitcnt lgkmcnt(0)" ::: "memory");
    __builtin_amdgcn_s_barrier();
}

// ---------------------------------------------------------------------------
// Round-1 structure (best measured: 46.2 us) + balanced 128-row tile PAIRS.
//   wave-0 prologue: queue scan (closed form, max-plus wave scan) -> Rs/CUs.
//     Q(t) = relu(Q(t-1) - u_t) + d_t,  CU(t) = sum u,  R(t) = Q(t) + CU(t)
//   main: out[t,b,e] = sum_i C[t,i] * V[i,b,e],
//     C[t,i] = min(relu(R_i-CU_t),1) - min(relu(R_{i-1}-CU_t),1)  (0 for i>t)
//
// m in FOUR 128-row tiles (k-prefix amplification 2.5x; round-2's 64-row
// split was 4.5x and regressed). Tile MI needs 4(MI+1) BK=32 chunks; pair
// {MI0,MI3} = {MI1,MI2} = 20 chunks -> every block identical work, zero tail
// (round-1 defect: 4:1 spread, time-weighted occupancy 17.6%). Small tile
// first: the large tile's k-prefix re-read follows recent accesses.
//
// Pipeline (round-2 proven): double-buffered LDS, ONE barrier per chunk:
//   frag ds_reads from buf[cur] | fill(it+1) into buf[cur^1] |
//   global prefetch (1 chunk ahead, vmcnt never drained) | lgkmcnt+s_barrier |
//   MFMA. 128m x 128n per tile, 4 waves (2x2), 64x64 per wave, acc[4][4]
//   (64 VGPR, no spill -- round-4's acc[8][4] spilled to scratch, 10x traffic).
// Grid: 512 blocks (64b x 4n x 2pairs) x 256 threads, 2 blocks/CU (45 KB LDS).
// XCD swizzle: id bits [2:0] = b%8; resident pair on a CU shares (b, n0).
// ---------------------------------------------------------------------------
__global__ __launch_bounds__(256, 2) void gemm_fused_kernel(
        const float* __restrict__ V,    // [T(i)][B][E]
        const float* __restrict__ U,    // [T][B]
        const float* __restrict__ D,    // [T][B]
        float* __restrict__ out) {      // [T(t)][B][E]
    const int id   = blockIdx.x;
    const int xcd  = id & 7;
    const int s    = (id >> 3) & 31;
    const int pr   = id >> 8;             // pair 0: {0,3}, pair 1: {1,2}
    const int b    = xcd + 8 * (s & 7);
    const int n0   = (s >> 3) * 128;
    const int MIa  = pr;                  // 0 or 1  (small tile first)
    const int MIb  = 3 - pr;              // 3 or 2
    const int Ka   = 4 * (MIa + 1);       // 4 or 8
    const int NIT  = 20;                  // Ka + 4*(MIb+1), same for both pairs

    __shared__ __align__(16) unsigned short As[2][128 * 40];  // [t][i] stride 40
    __shared__ __align__(16) unsigned short Bs[2][128 * 40];  // [e][i] stride 40
    __shared__ __align__(16) float Rs[TT];
    __shared__ __align__(16) float CUs[TT];

    const int tid  = threadIdx.x;
    const int wave = tid >> 6;
    const int lane = tid & 63;

    // A-fill: thread owns row a_t, 16 contiguous i.
    const int a_t  = tid >> 1;            // 0..127
    const int a_i0 = (tid & 1) * 16;      // 0 or 16
    // B-fill: thread owns 8k x 2e micro-tile.
    const int b_k8 = wave * 8;            // 0..24
    const int b_e2 = lane * 2;            // 0..126
    // Fragments: 2x2 waves, 64m x 64n per wave.
    const int wm   = (wave >> 1) * 64;
    const int wn   = (wave & 1) * 64;
    const int frow = lane & 15;
    const int quad = lane >> 4;

    const float* Vb = V + (size_t)b * EE + n0 + b_e2;   // + k*(BB*EE)

    // Prefetch chunk 0 (k=0 for tile a); latency hides under the scan.
    float2 v[8];
    #pragma unroll
    for (int r = 0; r < 8; ++r)
        v[r] = *(const float2*)(Vb + (size_t)(b_k8 + r) * (BB * EE));

    // ---- In-block scan (wave 0 only): R/CU for batch b into LDS ----
    if (wave == 0) {
        float u[8], d[8];
        #pragma unroll
        for (int j = 0; j < 8; ++j) {
            u[j] = U[(lane * 8 + j) * BB + b];
            d[j] = D[(lane * 8 + j) * BB + b];
        }
        float A = 0.f, Bv = -1e30f, S = 0.f;
        #pragma unroll
        for (int j = 0; j < 8; ++j) {
            const float a = d[j] - u[j];
            Bv = fmaxf(Bv + a, d[j]);
            A += a;
            S += u[j];
        }
        #pragma unroll
        for (int off = 1; off < 64; off <<= 1) {
            const float Ap = __shfl_up(A, off);
            const float Bp = __shfl_up(Bv, off);
            const float Sp = __shfl_up(S, off);
            if (lane >= off) {
                Bv = fmaxf(Bp + A, Bv);
                A  = A + Ap;
                S  = S + Sp;
            }
        }
        float Aex = __shfl_up(A, 1), Bex = __shfl_up(Bv, 1), Sex = __shfl_up(S, 1);
        if (lane == 0) { Aex = 0.f; Bex = -1e30f; Sex = 0.f; }
        float Q  = fmaxf(Aex, Bex);
        float cu = Sex;
        float rv[8], cv[8];
        #pragma unroll
        for (int j = 0; j < 8; ++j) {
            cu += u[j];
            Q = fmaxf(Q - u[j], 0.f) + d[j];
            rv[j] = Q + cu;
            cv[j] = cu;
        }
        *(float4*)(Rs  + lane * 8)     = make_float4(rv[0], rv[1], rv[2], rv[3]);
        *(float4*)(Rs  + lane * 8 + 4) = make_float4(rv[4], rv[5], rv[6], rv[7]);
        *(float4*)(CUs + lane * 8)     = make_float4(cv[0], cv[1], cv[2], cv[3]);
        *(float4*)(CUs + lane * 8 + 4) = make_float4(cv[4], cv[5], cv[6], cv[7]);
    }
    barrier_lds_only();                   // publishes Rs/CUs; v stays in flight

    const float cuA = CUs[MIa * 128 + a_t];
    const float cuB = CUs[MIb * 128 + a_t];

    // Stage A (closed form) + B (pack prefetched V) for iteration it_t.
    auto fill = [&](int it_t, int buf) {
        const bool inB = (it_t >= Ka);
        const int  MI  = inB ? MIb : MIa;
        const int  kk  = inB ? (it_t - Ka) : it_t;
        const float cu_t = inB ? cuB : cuA;
        const int  m0  = MI * 128;
        const int  k0  = kk * 32;
        // ---- A: 16 coeffs per thread ----
        {
            const int i = k0 + a_i0;
            const float4 r0 = *(const float4*)(Rs + i);
            const float4 r1 = *(const float4*)(Rs + i + 4);
            const float4 r2 = *(const float4*)(Rs + i + 8);
            const float4 r3 = *(const float4*)(Rs + i + 12);
            const float rv[16] = {r0.x, r0.y, r0.z, r0.w, r1.x, r1.y, r1.z, r1.w,
                                  r2.x, r2.y, r2.z, r2.w, r3.x, r3.y, r3.z, r3.w};
            const float prev = (i == 0) ? 0.f : Rs[i - 1];
            float pvp = fminf(fmaxf(prev - cu_t, 0.f), 1.f);
            float c[16];
            if (k0 < m0) {                    // strictly below diagonal
                #pragma unroll
                for (int j = 0; j < 16; ++j) {
                    const float pv = fminf(fmaxf(rv[j] - cu_t, 0.f), 1.f);
                    c[j] = pv - pvp;
                    pvp = pv;
                }
            } else {                          // diagonal chunk: zero for i > t
                const int t = m0 + a_t;
                #pragma unroll
                for (int j = 0; j < 16; ++j) {
                    const float pv = fminf(fmaxf(rv[j] - cu_t, 0.f), 1.f);
                    c[j] = (i + j <= t) ? (pv - pvp) : 0.f;
                    pvp = pv;
                }
            }
            uint4 w0, w1;
            w0.x = bpack(c[0], c[1]);   w0.y = bpack(c[2], c[3]);
            w0.z = bpack(c[4], c[5]);   w0.w = bpack(c[6], c[7]);
            w1.x = bpack(c[8], c[9]);   w1.y = bpack(c[10], c[11]);
            w1.z = bpack(c[12], c[13]); w1.w = bpack(c[14], c[15]);
            *(uint4*)(As[buf] + a_t * 40 + a_i0)     = w0;
            *(uint4*)(As[buf] + a_t * 40 + a_i0 + 8) = w1;
        }
        // ---- B: pack prefetched 8k x 2e of V, register transpose ----
        {
            uint4 p0, p1;
            p0.x = bpack(v[0].x, v[1].x); p0.y = bpack(v[2].x, v[3].x);
            p0.z = bpack(v[4].x, v[5].x); p0.w = bpack(v[6].x, v[7].x);
            p1.x = bpack(v[0].y, v[1].y); p1.y = bpack(v[2].y, v[3].y);
            p1.z = bpack(v[4].y, v[5].y); p1.w = bpack(v[6].y, v[7].y);
            *(uint4*)(Bs[buf] + b_e2 * 40 + b_k8)       = p0;
            *(uint4*)(Bs[buf] + (b_e2 + 1) * 40 + b_k8) = p1;
        }
    };

    // Issue global V loads for iteration it_t (consumed by fill(it_t)).
    auto prefetch = [&](int it_t) {
        const int kk = (it_t >= Ka) ? (it_t - Ka) : it_t;
        const float* vp = Vb + (size_t)(kk * 32 + b_k8) * (BB * EE);
        #pragma unroll
        for (int r = 0; r < 8; ++r)
            v[r] = *(const float2*)(vp + (size_t)r * (BB * EE));
    };

    f32x4 acc[4][4];
    #pragma unroll
    for (int mi = 0; mi < 4; ++mi)
        #pragma unroll
        for (int ni = 0; ni < 4; ++ni)
            acc[mi][ni] = f32x4{0.f, 0.f, 0.f, 0.f};

    // Epilogue: C/D layout col=lane&15, row=quad*4+r (m89/m91 verified).
    auto epilogue = [&](int m0t) {
        #pragma unroll
        for (int mi = 0; mi < 4; ++mi) {
            #pragma unroll
            for (int r = 0; r < 4; ++r) {
                const int t = m0t + wm + mi * 16 + quad * 4 + r;
                float* orow = out + ((size_t)t * BB + b) * EE + n0 + wn + frow;
                #pragma unroll
                for (int ni = 0; ni < 4; ++ni)
                    orow[ni * 16] = acc[mi][ni][r];
            }
        }
    };

    // Prologue: stage iteration 0 into buf 0, prefetch iteration 1.
    fill(0, 0);
    prefetch(1);
    barrier_lds_only();

    for (int it = 0; it < NIT; ++it) {
        const int cur = it & 1;

        bf16x8 af[4], bf[4];
        #pragma unroll
        for (int mi = 0; mi < 4; ++mi)
            af[mi] = *(const bf16x8*)(As[cur] + (wm + mi * 16 + frow) * 40 + quad * 8);
        #pragma unroll
        for (int ni = 0; ni < 4; ++ni)
            bf[ni] = *(const bf16x8*)(Bs[cur] + (wn + ni * 16 + frow) * 40 + quad * 8);

        if (it + 1 < NIT) {
            fill(it + 1, cur ^ 1);        // writes go to the OTHER buffer
            if (it + 2 < NIT) prefetch(it + 2);
        }

        barrier_lds_only();               // drains LDS only; vmcnt in flight

        #pragma unroll
        for (int mi = 0; mi < 4; ++mi)
            #pragma unroll
            for (int ni = 0; ni < 4; ++ni)
                acc[mi][ni] = __builtin_amdgcn_mfma_f32_16x16x32_bf16(
                    af[mi], bf[ni], acc[mi][ni], 0, 0, 0);

        if (it == Ka - 1) {               // small tile complete: flush + reset
            epilogue(MIa * 128);
            #pragma unroll
            for (int mi = 0; mi < 4; ++mi)
                #pragma unroll
                for (int ni = 0; ni < 4; ++ni)
                    acc[mi][ni] = f32x4{0.f, 0.f, 0.f, 0.f};
        }
    }
    epilogue(MIb * 128);
}

extern "C" void kernel_launch(void* const* d_in, const int* in_sizes, int n_in,
                              void* d_out, int out_size, void* d_ws, size_t ws_size,
                              hipStream_t stream) {
    const float* V = (const float*)d_in[0];   // [T,B,E]
    const float* U = (const float*)d_in[1];   // [T,B]
    const float* D = (const float*)d_in[2];   // [T,B]
    float* out = (float*)d_out;               // [T,B,E]

    gemm_fused_kernel<<<dim3(512), dim3(256), 0, stream>>>(V, U, D, out);
}